// Round 7
// baseline (49.937 us; speedup 1.0000x reference)
//
#include <hip/hip_runtime.h>

// MultiHeadAttention — fused per-token head-mixing attention.
// B=32, S=2048 -> 65536 tokens; E=128; HEADS=32; HEAD_DIM=4.
// out[t] = softmax_over_kh( Q(t)K(t)^T * 0.5 ) V(t)  @ Wo^T + bo.
//
// R7 (from 46us R6): amortize per-wave fixed cost — R3-R6 all launched 8192
// waves and all took ~46us (178 waves/us) regardless of structure; per-wave
// overhead (launch + cold-start latency + barriers) is the clock.
//  - BT 16->64 tokens/block, still 128 threads -> grid 1024, 2048 waves.
//  - Phase 1: x-fragments for 4 token-groups hoisted (64 VGPR); each weight
//    fragment reused over 4 token-tiles (weight L2 traffic 512->128 MB).
//  - Phase 2: 16 pair-iterations of the proven R6 MFMA body (2-token ILP).
//  - Phase 3: Wo fragments hoisted, reused over 4 token-groups.
//  - LDS 52224 B -> 3 blocks/CU. attended aliases qs.
//  - NO min-waves launch-bounds clause (R2 lesson: forced spills).

#define TOKENS (32 * 2048)
#define E 128
#define NH 32
#define BT 64           // tokens per block
#define THREADS 128     // 2 waves
#define LPITCH 136      // f16 elems per LDS token row (272 B)

typedef __attribute__((ext_vector_type(4))) float f32x4;
typedef __attribute__((ext_vector_type(16))) float f32x16;
typedef __fp16 h8_t __attribute__((ext_vector_type(8)));

#if __has_builtin(__builtin_amdgcn_exp2f)
#define EXP2F __builtin_amdgcn_exp2f
#else
#define EXP2F exp2f
#endif

#if __has_builtin(__builtin_amdgcn_rcpf)
#define RCPF __builtin_amdgcn_rcpf
#else
#define RCPF(x) (1.0f / (x))
#endif

static __device__ __forceinline__ unsigned pk16(float a, float b) {
    return __builtin_bit_cast(unsigned, __builtin_amdgcn_cvt_pkrtz(a, b));
}

static __device__ __forceinline__ f32x16 zero16() {
    f32x16 z;
#pragma unroll
    for (int i = 0; i < 16; ++i) z[i] = 0.f;
    return z;
}

// V' LDS permutation: p(kh) groups the 8 kh needed by PV A-fragment lane
// (c32,gg) half h into one contiguous 16B run at halfword offset d*32+16h+8gg.
static __device__ __forceinline__ int vperm(int kh) {
    return ((kh >> 4) & 1) * 16 + ((kh >> 2) & 1) * 8 + ((kh >> 3) & 1) * 4 + (kh & 3);
}

// ---------------------------------------------------------------------------
// Prelude: pack Wq,Wk,Wv,Wo (fp32, [out=128][in=128]) into f16 MFMA fragment
// order: wpk[proj][nt(8)][ks(4)][lane(64)][j(8)]; for lane l (c=l&15, g=l>>4):
// elem j = W[nt*16+c][ks*32 + g*8 + j].  Wk pre-scaled by 0.5*log2(e).
// ---------------------------------------------------------------------------
__global__ void pack_w(const float* __restrict__ Wq, const float* __restrict__ Wk,
                       const float* __restrict__ Wv, const float* __restrict__ Wo,
                       __fp16* __restrict__ wpk) {
    int idx = blockIdx.x * blockDim.x + threadIdx.x;   // 4*8*4*64 = 8192
    if (idx >= 4 * 8 * 4 * 64) return;
    int lane = idx & 63;
    int ks   = (idx >> 6) & 3;
    int nt   = (idx >> 8) & 7;
    int proj = idx >> 11;
    const float* W = (proj == 0) ? Wq : (proj == 1) ? Wk : (proj == 2) ? Wv : Wo;
    float scl = (proj == 1) ? 0.72134752044448170f : 1.0f;  // 0.5*log2(e)
    int c = lane & 15, g = lane >> 4;
    const float* src = W + (size_t)(nt * 16 + c) * E + ks * 32 + g * 8;
    __fp16* dst = wpk + (size_t)idx * 8;
#pragma unroll
    for (int j = 0; j < 8; ++j) dst[j] = (__fp16)(src[j] * scl);
}

// ---------------------------------------------------------------------------
// Main fused kernel: 64 tokens per block, 2 waves.
// ---------------------------------------------------------------------------
__global__ __launch_bounds__(THREADS) void mha_fused(
        const float* __restrict__ x, const __fp16* __restrict__ wpk,
        const float* __restrict__ bo, float* __restrict__ out) {
    __shared__ __align__(16) __fp16 qs [BT * LPITCH];  // Q rows, then attended
    __shared__ __align__(16) __fp16 ksh[BT * LPITCH];  // K*cexp rows [tok][kh*4+d]
    __shared__ __align__(16) __fp16 vth[BT * LPITCH];  // V'' [tok][d*32+p(kh)]

    const int tid  = threadIdx.x;
    const int wave = tid >> 6;
    const int lane = tid & 63;
    const int c = lane & 15, g = lane >> 4;
    const int bt0 = blockIdx.x * BT;

    // ---------------- Phase 1: Q,K,V projections (A=W, B=x swap) -----------
    {
        // x fragments for 4 token-groups (lane c = token within group)
        h8_t afrag[4][4];
#pragma unroll
        for (int tg = 0; tg < 4; ++tg) {
            const float* xrow = x + (size_t)(bt0 + tg * 16 + c) * E;
#pragma unroll
            for (int ks2 = 0; ks2 < 4; ++ks2) {
                const float* p = xrow + ks2 * 32 + g * 8;
                float4 v0 = *(const float4*)(p);
                float4 v1 = *(const float4*)(p + 4);
                uint4 au;
                au.x = pk16(v0.x, v0.y);
                au.y = pk16(v0.z, v0.w);
                au.z = pk16(v1.x, v1.y);
                au.w = pk16(v1.z, v1.w);
                afrag[tg][ks2] = __builtin_bit_cast(h8_t, au);
            }
        }

        // nc = 2*i + wave -> proj = i>>2 (valid: proj blocks are 8 wide)
#pragma unroll
        for (int i = 0; i < 12; ++i) {
            int nc   = i * 2 + wave;
            int proj = i >> 2;            // 0:Q 1:K 2:V
            int nt   = nc & 7;
            const __fp16* wb = wpk + ((size_t)((proj * 8 + nt) * 4) * 64 + lane) * 8;
            h8_t wf[4];
#pragma unroll
            for (int ks2 = 0; ks2 < 4; ++ks2)
                wf[ks2] = *(const h8_t*)(wb + (size_t)ks2 * 64 * 8);
#pragma unroll
            for (int tg = 0; tg < 4; ++tg) {
                f32x4 acc = {0.f, 0.f, 0.f, 0.f};
#pragma unroll
                for (int ks2 = 0; ks2 < 4; ++ks2)
                    acc = __builtin_amdgcn_mfma_f32_16x16x32_f16(wf[ks2], afrag[tg][ks2], acc, 0, 0, 0);
                int tok = tg * 16 + c;    // C[m=w_row][n=token]
                if (proj < 2) {
                    __fp16* dst = proj ? ksh : qs;
                    uint2 st = make_uint2(pk16(acc[0], acc[1]), pk16(acc[2], acc[3]));
                    *(uint2*)(dst + tok * LPITCH + nt * 16 + g * 4) = st;   // one b64
                } else {
                    int vp = vperm(nt * 4 + g);   // kh = nt*4+g, d = r2
#pragma unroll
                    for (int r2 = 0; r2 < 4; ++r2)
                        vth[tok * LPITCH + r2 * 32 + vp] = (__fp16)acc[r2];
                }
            }
        }
    }
    __syncthreads();

    // ---------------- Phase 2: per-token attention, 2-token ILP ------------
    // S^T[kh][qh] = mfma32x32(A=K', B=Q) (k=d in slots 0-3);
    // O/denom     = mfma32x32(A=V'+ones-row4, B=exp(S)) x2 halves.
    {
        const int c32 = lane & 31;
        const int gg  = lane >> 5;
        const uint4 ONES4 = make_uint4(0x3C003C00u, 0x3C003C00u, 0x3C003C00u, 0x3C003C00u);
        const f32x16 z = zero16();
        const int tb = wave * 32;
#pragma unroll 1
        for (int pr = 0; pr < 16; ++pr) {
            const int t0 = tb + pr * 2, t1 = t0 + 1;
            const __fp16* v0r = vth + t0 * LPITCH;
            const __fp16* v1r = vth + t1 * LPITCH;

            uint4 ka0 = {0u,0u,0u,0u}, qa0 = {0u,0u,0u,0u};
            uint4 ka1 = {0u,0u,0u,0u}, qa1 = {0u,0u,0u,0u};
            if (gg == 0) {
                uint2 t;
                t = *(const uint2*)(ksh + t0 * LPITCH + c32 * 4); ka0.x = t.x; ka0.y = t.y;
                t = *(const uint2*)(qs  + t0 * LPITCH + c32 * 4); qa0.x = t.x; qa0.y = t.y;
                t = *(const uint2*)(ksh + t1 * LPITCH + c32 * 4); ka1.x = t.x; ka1.y = t.y;
                t = *(const uint2*)(qs  + t1 * LPITCH + c32 * 4); qa1.x = t.x; qa1.y = t.y;
            }
            uint4 va00 = *(const uint4*)(v0r + (c32 & 3) * 32 + gg * 8);
            uint4 va01 = *(const uint4*)(v0r + (c32 & 3) * 32 + 16 + gg * 8);
            uint4 va10 = *(const uint4*)(v1r + (c32 & 3) * 32 + gg * 8);
            uint4 va11 = *(const uint4*)(v1r + (c32 & 3) * 32 + 16 + gg * 8);
            if (c32 == 4) { va00 = ONES4; va01 = ONES4; va10 = ONES4; va11 = ONES4; }

            f32x16 sc0 = __builtin_amdgcn_mfma_f32_32x32x16_f16(
                __builtin_bit_cast(h8_t, ka0), __builtin_bit_cast(h8_t, qa0), z, 0, 0, 0);
            f32x16 sc1 = __builtin_amdgcn_mfma_f32_32x32x16_f16(
                __builtin_bit_cast(h8_t, ka1), __builtin_bit_cast(h8_t, qa1), z, 0, 0, 0);

            uint4 p00u, p01u, p10u, p11u;
            {
                float e[16];
#pragma unroll
                for (int r = 0; r < 16; ++r) e[r] = EXP2F(sc0[r]);
                p00u = make_uint4(pk16(e[0], e[1]),  pk16(e[2], e[3]),
                                  pk16(e[4], e[5]),  pk16(e[6], e[7]));
                p01u = make_uint4(pk16(e[8], e[9]),  pk16(e[10], e[11]),
                                  pk16(e[12], e[13]), pk16(e[14], e[15]));
            }
            {
                float e[16];
#pragma unroll
                for (int r = 0; r < 16; ++r) e[r] = EXP2F(sc1[r]);
                p10u = make_uint4(pk16(e[0], e[1]),  pk16(e[2], e[3]),
                                  pk16(e[4], e[5]),  pk16(e[6], e[7]));
                p11u = make_uint4(pk16(e[8], e[9]),  pk16(e[10], e[11]),
                                  pk16(e[12], e[13]), pk16(e[14], e[15]));
            }

            f32x16 pv0 = __builtin_amdgcn_mfma_f32_32x32x16_f16(
                __builtin_bit_cast(h8_t, va00), __builtin_bit_cast(h8_t, p00u), z, 0, 0, 0);
            pv0 = __builtin_amdgcn_mfma_f32_32x32x16_f16(
                __builtin_bit_cast(h8_t, va01), __builtin_bit_cast(h8_t, p01u), pv0, 0, 0, 0);
            f32x16 pv1 = __builtin_amdgcn_mfma_f32_32x32x16_f16(
                __builtin_bit_cast(h8_t, va10), __builtin_bit_cast(h8_t, p10u), z, 0, 0, 0);
            pv1 = __builtin_amdgcn_mfma_f32_32x32x16_f16(
                __builtin_bit_cast(h8_t, va11), __builtin_bit_cast(h8_t, p11u), pv1, 0, 0, 0);

            // denom at row 4 -> lane (c32,1) reg0; O[d] at lane (c32,0) regs0-3
            float s0 = __shfl(pv0[0], c32 + 32, 64);
            float s1 = __shfl(pv1[0], c32 + 32, 64);
            float r0 = RCPF(s0), r1 = RCPF(s1);
            if (lane < 32) {
                uint2 st0 = make_uint2(pk16(pv0[0] * r0, pv0[1] * r0),
                                       pk16(pv0[2] * r0, pv0[3] * r0));
                uint2 st1 = make_uint2(pk16(pv1[0] * r1, pv1[1] * r1),
                                       pk16(pv1[2] * r1, pv1[3] * r1));
                *(uint2*)(qs + t0 * LPITCH + c32 * 4) = st0;   // attended aliases qs
                *(uint2*)(qs + t1 * LPITCH + c32 * 4) = st1;
            }
        }
    }
    __syncthreads();

    // ---------------- Phase 3: output projection + bias (A=Wo, B=at) -------
    {
        // Wo fragments hoisted (reused over 4 token-groups)
        h8_t wf[4][4];
#pragma unroll
        for (int i = 0; i < 4; ++i) {
            int nt = wave * 4 + i;
            const __fp16* wb = wpk + ((size_t)((3 * 8 + nt) * 4) * 64 + lane) * 8;
#pragma unroll
            for (int ks2 = 0; ks2 < 4; ++ks2)
                wf[i][ks2] = *(const h8_t*)(wb + (size_t)ks2 * 64 * 8);
        }
        float4 b4[4];
#pragma unroll
        for (int i = 0; i < 4; ++i)
            b4[i] = *(const float4*)(bo + (wave * 4 + i) * 16 + g * 4);

#pragma unroll
        for (int tg = 0; tg < 4; ++tg) {
            h8_t af[4];
#pragma unroll
            for (int ks2 = 0; ks2 < 4; ++ks2)
                af[ks2] = *(const h8_t*)(qs + (tg * 16 + c) * LPITCH + ks2 * 32 + g * 8);
#pragma unroll
            for (int i = 0; i < 4; ++i) {
                f32x4 acc = {0.f, 0.f, 0.f, 0.f};
#pragma unroll
                for (int ks2 = 0; ks2 < 4; ++ks2)
                    acc = __builtin_amdgcn_mfma_f32_16x16x32_f16(wf[i][ks2], af[ks2], acc, 0, 0, 0);
                int col0 = (wave * 4 + i) * 16 + g * 4;   // C[m=w_row][n=token]
                float4 st = make_float4(acc[0] + b4[i].x, acc[1] + b4[i].y,
                                        acc[2] + b4[i].z, acc[3] + b4[i].w);
                *(float4*)(out + (size_t)(bt0 + tg * 16 + c) * E + col0) = st;
            }
        }
    }
}

// ---------------------------------------------------------------------------
extern "C" void kernel_launch(void* const* d_in, const int* in_sizes, int n_in,
                              void* d_out, int out_size, void* d_ws, size_t ws_size,
                              hipStream_t stream) {
    const float* x  = (const float*)d_in[0];
    const float* Wq = (const float*)d_in[1];
    const float* Wk = (const float*)d_in[2];
    const float* Wv = (const float*)d_in[3];
    const float* Wo = (const float*)d_in[4];
    const float* bo = (const float*)d_in[5];
    __fp16* wpk = (__fp16*)d_ws;   // 4*8*4*64*8 f16 = 128 KiB
    float* out = (float*)d_out;

    pack_w<<<32, 256, 0, stream>>>(Wq, Wk, Wv, Wo, wpk);
    mha_fused<<<TOKENS / BT, THREADS, 0, stream>>>(x, wpk, bo, out);
}

// Round 8
// 42.172 us; speedup vs baseline: 1.1841x; 1.1841x over previous
//
#include <hip/hip_runtime.h>

// MultiHeadAttention — fused per-token head-mixing attention.
// B=32, S=2048 -> 65536 tokens; E=128; HEADS=32; HEAD_DIM=4.
// out[t] = softmax_over_kh( Q(t)K(t)^T * 0.5 ) V(t)  @ Wo^T + bo.
//
// R8 (from 46us plateau R3-R7): BARRIER-FREE wave-self-sufficient pipelines.
// Five structures all pinned at ~46us with ~60% of cycles idle (R7: VALU 27%,
// MFMA 11.5%, occupancy 11%) -> exposed latency under barrier convoys.
//  - Each wave owns 16 tokens END-TO-END: computes all 24 QKV column-tiles
//    (96 MFMAs), phase 2 (R6's proven 2-token-ILP MFMA body), all 8 Wo tiles.
//  - ZERO __syncthreads: same-wave LDS RAW ordered by lgkmcnt; waves fully
//    independent -> any resident wave can fill any other's stalls.
//  - LDS 26112 B/block (2 waves, private 13056 B slices) -> 6 blocks/CU,
//    12 waves/CU resource cap.
//  - Weights re-read per wave (~128 KB) stay L2-resident.
//  - NO min-waves launch-bounds clause (R2 lesson: forced spills).

#define TOKENS (32 * 2048)
#define E 128
#define NH 32
#define WTOK 16         // tokens per wave
#define THREADS 128     // 2 waves per block
#define LPITCH 136      // f16 elems per LDS token row (272 B)

typedef __attribute__((ext_vector_type(4))) float f32x4;
typedef __attribute__((ext_vector_type(16))) float f32x16;
typedef __fp16 h8_t __attribute__((ext_vector_type(8)));

#if __has_builtin(__builtin_amdgcn_exp2f)
#define EXP2F __builtin_amdgcn_exp2f
#else
#define EXP2F exp2f
#endif

#if __has_builtin(__builtin_amdgcn_rcpf)
#define RCPF __builtin_amdgcn_rcpf
#else
#define RCPF(x) (1.0f / (x))
#endif

static __device__ __forceinline__ unsigned pk16(float a, float b) {
    return __builtin_bit_cast(unsigned, __builtin_amdgcn_cvt_pkrtz(a, b));
}

static __device__ __forceinline__ f32x16 zero16() {
    f32x16 z;
#pragma unroll
    for (int i = 0; i < 16; ++i) z[i] = 0.f;
    return z;
}

// V' LDS permutation: p(kh) groups the 8 kh needed by PV A-fragment lane
// (c32,gg) half h into one contiguous 16B run at halfword offset d*32+16h+8gg.
static __device__ __forceinline__ int vperm(int kh) {
    return ((kh >> 4) & 1) * 16 + ((kh >> 2) & 1) * 8 + ((kh >> 3) & 1) * 4 + (kh & 3);
}

// ---------------------------------------------------------------------------
// Prelude: pack Wq,Wk,Wv,Wo (fp32, [out=128][in=128]) into f16 MFMA fragment
// order: wpk[proj][nt(8)][ks(4)][lane(64)][j(8)]; for lane l (c=l&15, g=l>>4):
// elem j = W[nt*16+c][ks*32 + g*8 + j].  Wk pre-scaled by 0.5*log2(e).
// ---------------------------------------------------------------------------
__global__ void pack_w(const float* __restrict__ Wq, const float* __restrict__ Wk,
                       const float* __restrict__ Wv, const float* __restrict__ Wo,
                       __fp16* __restrict__ wpk) {
    int idx = blockIdx.x * blockDim.x + threadIdx.x;   // 4*8*4*64 = 8192
    if (idx >= 4 * 8 * 4 * 64) return;
    int lane = idx & 63;
    int ks   = (idx >> 6) & 3;
    int nt   = (idx >> 8) & 7;
    int proj = idx >> 11;
    const float* W = (proj == 0) ? Wq : (proj == 1) ? Wk : (proj == 2) ? Wv : Wo;
    float scl = (proj == 1) ? 0.72134752044448170f : 1.0f;  // 0.5*log2(e)
    int c = lane & 15, g = lane >> 4;
    const float* src = W + (size_t)(nt * 16 + c) * E + ks * 32 + g * 8;
    __fp16* dst = wpk + (size_t)idx * 8;
#pragma unroll
    for (int j = 0; j < 8; ++j) dst[j] = (__fp16)(src[j] * scl);
}

// ---------------------------------------------------------------------------
// Main fused kernel: 2 independent 16-token waves per block, no barriers.
// ---------------------------------------------------------------------------
__global__ __launch_bounds__(THREADS) void mha_fused(
        const float* __restrict__ x, const __fp16* __restrict__ wpk,
        const float* __restrict__ bo, float* __restrict__ out) {
    __shared__ __align__(16) __fp16 qs [2 * WTOK * LPITCH];  // Q rows -> attended
    __shared__ __align__(16) __fp16 ksh[2 * WTOK * LPITCH];  // K*cexp [tok][kh*4+d]
    __shared__ __align__(16) __fp16 vth[2 * WTOK * LPITCH];  // V'' [tok][d*32+p(kh)]

    const int tid  = threadIdx.x;
    const int wave = tid >> 6;
    const int lane = tid & 63;
    const int c = lane & 15, g = lane >> 4;
    const int tbase = blockIdx.x * (2 * WTOK) + wave * WTOK;  // wave's first token

    __fp16* qsw = qs  + wave * WTOK * LPITCH;   // wave-private LDS slices
    __fp16* ksw = ksh + wave * WTOK * LPITCH;
    __fp16* vtw = vth + wave * WTOK * LPITCH;

    // ---------------- Phase 1: all 24 QKV column-tiles for own 16 tokens ---
    {
        h8_t afrag[4];     // x fragments, lane c = token, kappa(g,j)=g*8+j
        const float* xrow = x + (size_t)(tbase + c) * E;
#pragma unroll
        for (int ks2 = 0; ks2 < 4; ++ks2) {
            const float* p = xrow + ks2 * 32 + g * 8;
            float4 v0 = *(const float4*)(p);
            float4 v1 = *(const float4*)(p + 4);
            uint4 au;
            au.x = pk16(v0.x, v0.y);
            au.y = pk16(v0.z, v0.w);
            au.z = pk16(v1.x, v1.y);
            au.w = pk16(v1.z, v1.w);
            afrag[ks2] = __builtin_bit_cast(h8_t, au);
        }

#pragma unroll
        for (int nc = 0; nc < 24; ++nc) {
            int proj = nc >> 3;           // 0:Q 1:K 2:V (compile-time)
            int nt   = nc & 7;
            const __fp16* wb = wpk + ((size_t)((proj * 8 + nt) * 4) * 64 + lane) * 8;
            f32x4 acc = {0.f, 0.f, 0.f, 0.f};
#pragma unroll
            for (int ks2 = 0; ks2 < 4; ++ks2) {
                h8_t wf = *(const h8_t*)(wb + (size_t)ks2 * 64 * 8);
                // A=W (m=w_row), B=x (n=token): C[m=g*4+r2 (+nt*16)][n=c]
                acc = __builtin_amdgcn_mfma_f32_16x16x32_f16(wf, afrag[ks2], acc, 0, 0, 0);
            }
            if (proj < 2) {
                __fp16* dst = proj ? ksw : qsw;
                uint2 st = make_uint2(pk16(acc[0], acc[1]), pk16(acc[2], acc[3]));
                *(uint2*)(dst + c * LPITCH + nt * 16 + g * 4) = st;   // one b64
            } else {
                int vp = vperm(nt * 4 + g);   // kh = nt*4+g, d = r2
#pragma unroll
                for (int r2 = 0; r2 < 4; ++r2)
                    vtw[c * LPITCH + r2 * 32 + vp] = (__fp16)acc[r2];
            }
        }
    }
    // no barrier: same-wave LDS RAW ordered by lgkmcnt

    // ---------------- Phase 2: per-token attention, 2-token ILP ------------
    // S^T[kh][qh] = mfma32x32(A=K', B=Q) (k=d in slots 0-3);
    // O/denom     = mfma32x32(A=V'+ones-row4, B=exp(S)) x2 halves.
    {
        const int c32 = lane & 31;
        const int gg  = lane >> 5;
        const uint4 ONES4 = make_uint4(0x3C003C00u, 0x3C003C00u, 0x3C003C00u, 0x3C003C00u);
        const f32x16 z = zero16();
#pragma unroll 1
        for (int pr = 0; pr < 8; ++pr) {
            const int t0 = pr * 2, t1 = t0 + 1;
            const __fp16* v0r = vtw + t0 * LPITCH;
            const __fp16* v1r = vtw + t1 * LPITCH;

            uint4 ka0 = {0u,0u,0u,0u}, qa0 = {0u,0u,0u,0u};
            uint4 ka1 = {0u,0u,0u,0u}, qa1 = {0u,0u,0u,0u};
            if (gg == 0) {
                uint2 t;
                t = *(const uint2*)(ksw + t0 * LPITCH + c32 * 4); ka0.x = t.x; ka0.y = t.y;
                t = *(const uint2*)(qsw + t0 * LPITCH + c32 * 4); qa0.x = t.x; qa0.y = t.y;
                t = *(const uint2*)(ksw + t1 * LPITCH + c32 * 4); ka1.x = t.x; ka1.y = t.y;
                t = *(const uint2*)(qsw + t1 * LPITCH + c32 * 4); qa1.x = t.x; qa1.y = t.y;
            }
            uint4 va00 = *(const uint4*)(v0r + (c32 & 3) * 32 + gg * 8);
            uint4 va01 = *(const uint4*)(v0r + (c32 & 3) * 32 + 16 + gg * 8);
            uint4 va10 = *(const uint4*)(v1r + (c32 & 3) * 32 + gg * 8);
            uint4 va11 = *(const uint4*)(v1r + (c32 & 3) * 32 + 16 + gg * 8);
            if (c32 == 4) { va00 = ONES4; va01 = ONES4; va10 = ONES4; va11 = ONES4; }

            f32x16 sc0 = __builtin_amdgcn_mfma_f32_32x32x16_f16(
                __builtin_bit_cast(h8_t, ka0), __builtin_bit_cast(h8_t, qa0), z, 0, 0, 0);
            f32x16 sc1 = __builtin_amdgcn_mfma_f32_32x32x16_f16(
                __builtin_bit_cast(h8_t, ka1), __builtin_bit_cast(h8_t, qa1), z, 0, 0, 0);

            uint4 p00u, p01u, p10u, p11u;
            {
                float e[16];
#pragma unroll
                for (int r = 0; r < 16; ++r) e[r] = EXP2F(sc0[r]);
                p00u = make_uint4(pk16(e[0], e[1]),  pk16(e[2], e[3]),
                                  pk16(e[4], e[5]),  pk16(e[6], e[7]));
                p01u = make_uint4(pk16(e[8], e[9]),  pk16(e[10], e[11]),
                                  pk16(e[12], e[13]), pk16(e[14], e[15]));
            }
            {
                float e[16];
#pragma unroll
                for (int r = 0; r < 16; ++r) e[r] = EXP2F(sc1[r]);
                p10u = make_uint4(pk16(e[0], e[1]),  pk16(e[2], e[3]),
                                  pk16(e[4], e[5]),  pk16(e[6], e[7]));
                p11u = make_uint4(pk16(e[8], e[9]),  pk16(e[10], e[11]),
                                  pk16(e[12], e[13]), pk16(e[14], e[15]));
            }

            f32x16 pv0 = __builtin_amdgcn_mfma_f32_32x32x16_f16(
                __builtin_bit_cast(h8_t, va00), __builtin_bit_cast(h8_t, p00u), z, 0, 0, 0);
            pv0 = __builtin_amdgcn_mfma_f32_32x32x16_f16(
                __builtin_bit_cast(h8_t, va01), __builtin_bit_cast(h8_t, p01u), pv0, 0, 0, 0);
            f32x16 pv1 = __builtin_amdgcn_mfma_f32_32x32x16_f16(
                __builtin_bit_cast(h8_t, va10), __builtin_bit_cast(h8_t, p10u), z, 0, 0, 0);
            pv1 = __builtin_amdgcn_mfma_f32_32x32x16_f16(
                __builtin_bit_cast(h8_t, va11), __builtin_bit_cast(h8_t, p11u), pv1, 0, 0, 0);

            // denom at row 4 -> lane (c32,1) reg0; O[d] at lane (c32,0) regs0-3
            float s0 = __shfl(pv0[0], c32 + 32, 64);
            float s1 = __shfl(pv1[0], c32 + 32, 64);
            float r0 = RCPF(s0), r1 = RCPF(s1);
            if (lane < 32) {
                uint2 st0 = make_uint2(pk16(pv0[0] * r0, pv0[1] * r0),
                                       pk16(pv0[2] * r0, pv0[3] * r0));
                uint2 st1 = make_uint2(pk16(pv1[0] * r1, pv1[1] * r1),
                                       pk16(pv1[2] * r1, pv1[3] * r1));
                *(uint2*)(qsw + t0 * LPITCH + c32 * 4) = st0;  // attended aliases Q
                *(uint2*)(qsw + t1 * LPITCH + c32 * 4) = st1;
            }
        }
    }
    // no barrier

    // ---------------- Phase 3: output projection + bias (A=Wo, B=at) -------
    {
        h8_t af[4];
#pragma unroll
        for (int ks2 = 0; ks2 < 4; ++ks2)
            af[ks2] = *(const h8_t*)(qsw + c * LPITCH + ks2 * 32 + g * 8);
#pragma unroll
        for (int nt = 0; nt < 8; ++nt) {
            const __fp16* wb = wpk + ((size_t)((3 * 8 + nt) * 4) * 64 + lane) * 8;
            f32x4 acc = {0.f, 0.f, 0.f, 0.f};
#pragma unroll
            for (int ks2 = 0; ks2 < 4; ++ks2) {
                h8_t b = *(const h8_t*)(wb + (size_t)ks2 * 64 * 8);
                acc = __builtin_amdgcn_mfma_f32_16x16x32_f16(b, af[ks2], acc, 0, 0, 0);
            }
            int col0 = nt * 16 + g * 4;           // C[m=w_row][n=token c]
            float4 b4 = *(const float4*)(bo + col0);
            float4 st = make_float4(acc[0] + b4.x, acc[1] + b4.y,
                                    acc[2] + b4.z, acc[3] + b4.w);
            *(float4*)(out + (size_t)(tbase + c) * E + col0) = st;
        }
    }
}

// ---------------------------------------------------------------------------
extern "C" void kernel_launch(void* const* d_in, const int* in_sizes, int n_in,
                              void* d_out, int out_size, void* d_ws, size_t ws_size,
                              hipStream_t stream) {
    const float* x  = (const float*)d_in[0];
    const float* Wq = (const float*)d_in[1];
    const float* Wk = (const float*)d_in[2];
    const float* Wv = (const float*)d_in[3];
    const float* Wo = (const float*)d_in[4];
    const float* bo = (const float*)d_in[5];
    __fp16* wpk = (__fp16*)d_ws;   // 4*8*4*64*8 f16 = 128 KiB
    float* out = (float*)d_out;

    pack_w<<<32, 256, 0, stream>>>(Wq, Wk, Wv, Wo, wpk);
    mha_fused<<<TOKENS / (2 * WTOK), THREADS, 0, stream>>>(x, wpk, bo, out);
}

// Round 9
// 41.528 us; speedup vs baseline: 1.2025x; 1.0155x over previous
//
#include <hip/hip_runtime.h>

// MultiHeadAttention — fused per-token head-mixing attention.
// B=32, S=2048 -> 65536 tokens; E=128; HEADS=32; HEAD_DIM=4.
// out[t] = softmax_over_kh( Q(t)K(t)^T * 0.5 ) V(t)  @ Wo^T + bo.
//
// R9 (from 42us R8): same barrier-free wave-self-sufficient structure; attack
// INTRA-WAVE exposed latency (R8: ~14k cyc/wave of serialized L2/LDS round
// trips, only ~1.3-3 runnable waves/SIMD to hide them; VGPR=88 showed the
// compiler never pipelined the 24 weight-load rounds).
//  - Phase 1: depth-3 circular prefetch of weight fragments (wfb[3][4],
//    static idx under full unroll) -> 8-12 L2 loads in flight.
//  - Phase 2: double-buffered pair inputs (ds_reads + V frags for pair pr+1
//    issued before computing pair pr; exp/pack block hides LDS latency).
//  - Phase 3: depth-3 Wo prefetch.
//  - Math/layouts bit-identical to R8 (passed). No barriers. No min-waves
//    launch-bounds clause (R2 spill lesson). Target VGPR <= 168.

#define TOKENS (32 * 2048)
#define E 128
#define NH 32
#define WTOK 16         // tokens per wave
#define THREADS 128     // 2 waves per block
#define LPITCH 136      // f16 elems per LDS token row (272 B)

typedef __attribute__((ext_vector_type(4))) float f32x4;
typedef __attribute__((ext_vector_type(16))) float f32x16;
typedef __fp16 h8_t __attribute__((ext_vector_type(8)));

#if __has_builtin(__builtin_amdgcn_exp2f)
#define EXP2F __builtin_amdgcn_exp2f
#else
#define EXP2F exp2f
#endif

#if __has_builtin(__builtin_amdgcn_rcpf)
#define RCPF __builtin_amdgcn_rcpf
#else
#define RCPF(x) (1.0f / (x))
#endif

static __device__ __forceinline__ unsigned pk16(float a, float b) {
    return __builtin_bit_cast(unsigned, __builtin_amdgcn_cvt_pkrtz(a, b));
}

static __device__ __forceinline__ f32x16 zero16() {
    f32x16 z;
#pragma unroll
    for (int i = 0; i < 16; ++i) z[i] = 0.f;
    return z;
}

// V' LDS permutation: p(kh) groups the 8 kh needed by PV A-fragment lane
// (c32,gg) half h into one contiguous 16B run at halfword offset d*32+16h+8gg.
static __device__ __forceinline__ int vperm(int kh) {
    return ((kh >> 4) & 1) * 16 + ((kh >> 2) & 1) * 8 + ((kh >> 3) & 1) * 4 + (kh & 3);
}

// ---------------------------------------------------------------------------
// Prelude: pack Wq,Wk,Wv,Wo (fp32, [out=128][in=128]) into f16 MFMA fragment
// order: wpk[proj][nt(8)][ks(4)][lane(64)][j(8)]; for lane l (c=l&15, g=l>>4):
// elem j = W[nt*16+c][ks*32 + g*8 + j].  Wk pre-scaled by 0.5*log2(e).
// ---------------------------------------------------------------------------
__global__ void pack_w(const float* __restrict__ Wq, const float* __restrict__ Wk,
                       const float* __restrict__ Wv, const float* __restrict__ Wo,
                       __fp16* __restrict__ wpk) {
    int idx = blockIdx.x * blockDim.x + threadIdx.x;   // 4*8*4*64 = 8192
    if (idx >= 4 * 8 * 4 * 64) return;
    int lane = idx & 63;
    int ks   = (idx >> 6) & 3;
    int nt   = (idx >> 8) & 7;
    int proj = idx >> 11;
    const float* W = (proj == 0) ? Wq : (proj == 1) ? Wk : (proj == 2) ? Wv : Wo;
    float scl = (proj == 1) ? 0.72134752044448170f : 1.0f;  // 0.5*log2(e)
    int c = lane & 15, g = lane >> 4;
    const float* src = W + (size_t)(nt * 16 + c) * E + ks * 32 + g * 8;
    __fp16* dst = wpk + (size_t)idx * 8;
#pragma unroll
    for (int j = 0; j < 8; ++j) dst[j] = (__fp16)(src[j] * scl);
}

// ---------------------------------------------------------------------------
// Main fused kernel: 2 independent 16-token waves per block, no barriers.
// ---------------------------------------------------------------------------
__global__ __launch_bounds__(THREADS) void mha_fused(
        const float* __restrict__ x, const __fp16* __restrict__ wpk,
        const float* __restrict__ bo, float* __restrict__ out) {
    __shared__ __align__(16) __fp16 qs [2 * WTOK * LPITCH];  // Q rows -> attended
    __shared__ __align__(16) __fp16 ksh[2 * WTOK * LPITCH];  // K*cexp [tok][kh*4+d]
    __shared__ __align__(16) __fp16 vth[2 * WTOK * LPITCH];  // V'' [tok][d*32+p(kh)]

    const int tid  = threadIdx.x;
    const int wave = tid >> 6;
    const int lane = tid & 63;
    const int c = lane & 15, g = lane >> 4;
    const int tbase = blockIdx.x * (2 * WTOK) + wave * WTOK;  // wave's first token

    __fp16* qsw = qs  + wave * WTOK * LPITCH;   // wave-private LDS slices
    __fp16* ksw = ksh + wave * WTOK * LPITCH;
    __fp16* vtw = vth + wave * WTOK * LPITCH;

    // ---------------- Phase 1: all 24 QKV column-tiles for own 16 tokens ---
    // Depth-3 circular prefetch of weight fragments (nc index is address nc
    // directly: proj*8+nt == nc).
    {
        h8_t afrag[4];     // x fragments, lane c = token, kappa(g,j)=g*8+j
        const float* xrow = x + (size_t)(tbase + c) * E;
#pragma unroll
        for (int ks2 = 0; ks2 < 4; ++ks2) {
            const float* p = xrow + ks2 * 32 + g * 8;
            float4 v0 = *(const float4*)(p);
            float4 v1 = *(const float4*)(p + 4);
            uint4 au;
            au.x = pk16(v0.x, v0.y);
            au.y = pk16(v0.z, v0.w);
            au.z = pk16(v1.x, v1.y);
            au.w = pk16(v1.z, v1.w);
            afrag[ks2] = __builtin_bit_cast(h8_t, au);
        }

        h8_t wfb[3][4];    // circular prefetch buffers
#pragma unroll
        for (int p = 0; p < 3; ++p) {
            const __fp16* wb = wpk + ((size_t)(p * 4) * 64 + lane) * 8;
#pragma unroll
            for (int k = 0; k < 4; ++k)
                wfb[p][k] = *(const h8_t*)(wb + (size_t)k * 64 * 8);
        }

#pragma unroll
        for (int nc = 0; nc < 24; ++nc) {
            const int proj = nc >> 3;     // 0:Q 1:K 2:V (compile-time)
            const int nt   = nc & 7;
            const int slot = nc % 3;      // compile-time under full unroll
            f32x4 acc = {0.f, 0.f, 0.f, 0.f};
#pragma unroll
            for (int ks2 = 0; ks2 < 4; ++ks2) {
                // A=W (m=w_row), B=x (n=token): C[m=g*4+r2 (+nt*16)][n=c]
                acc = __builtin_amdgcn_mfma_f32_16x16x32_f16(wfb[slot][ks2], afrag[ks2], acc, 0, 0, 0);
            }
            if (nc + 3 < 24) {            // refill this slot for nc+3
                const __fp16* wb = wpk + ((size_t)((nc + 3) * 4) * 64 + lane) * 8;
#pragma unroll
                for (int k = 0; k < 4; ++k)
                    wfb[slot][k] = *(const h8_t*)(wb + (size_t)k * 64 * 8);
            }
            if (proj < 2) {
                __fp16* dst = proj ? ksw : qsw;
                uint2 st = make_uint2(pk16(acc[0], acc[1]), pk16(acc[2], acc[3]));
                *(uint2*)(dst + c * LPITCH + nt * 16 + g * 4) = st;   // one b64
            } else {
                int vp = vperm(nt * 4 + g);   // kh = nt*4+g, d = r2
#pragma unroll
                for (int r2 = 0; r2 < 4; ++r2)
                    vtw[c * LPITCH + r2 * 32 + vp] = (__fp16)acc[r2];
            }
        }
    }
    // no barrier: same-wave LDS RAW ordered by lgkmcnt

    // ---------------- Phase 2: per-token attention, 2-token ILP ------------
    // S^T[kh][qh] = mfma32x32(A=K', B=Q) (k=d in slots 0-3);
    // O/denom     = mfma32x32(A=V'+ones-row4, B=exp(S)) x2 halves.
    // Double-buffered inputs: pair pr+1's LDS loads issue before pair pr's
    // compute; exp/pack block hides the LDS latency.
    {
        const int c32 = lane & 31;
        const int gg  = lane >> 5;
        const uint4 ONES4 = make_uint4(0x3C003C00u, 0x3C003C00u, 0x3C003C00u, 0x3C003C00u);
        const f32x16 z = zero16();

        uint4 ka0[2], qa0[2], ka1[2], qa1[2];
        uint4 va00[2], va01[2], va10[2], va11[2];

#define LOADPAIR(s, pr_) do {                                                  \
        const int t0_ = (pr_) * 2, t1_ = t0_ + 1;                              \
        ka0[s] = qa0[s] = ka1[s] = qa1[s] = make_uint4(0u, 0u, 0u, 0u);        \
        if (gg == 0) {                                                         \
            uint2 t_;                                                          \
            t_ = *(const uint2*)(ksw + t0_ * LPITCH + c32 * 4); ka0[s].x = t_.x; ka0[s].y = t_.y; \
            t_ = *(const uint2*)(qsw + t0_ * LPITCH + c32 * 4); qa0[s].x = t_.x; qa0[s].y = t_.y; \
            t_ = *(const uint2*)(ksw + t1_ * LPITCH + c32 * 4); ka1[s].x = t_.x; ka1[s].y = t_.y; \
            t_ = *(const uint2*)(qsw + t1_ * LPITCH + c32 * 4); qa1[s].x = t_.x; qa1[s].y = t_.y; \
        }                                                                      \
        va00[s] = *(const uint4*)(vtw + t0_ * LPITCH + (c32 & 3) * 32 + gg * 8);      \
        va01[s] = *(const uint4*)(vtw + t0_ * LPITCH + (c32 & 3) * 32 + 16 + gg * 8); \
        va10[s] = *(const uint4*)(vtw + t1_ * LPITCH + (c32 & 3) * 32 + gg * 8);      \
        va11[s] = *(const uint4*)(vtw + t1_ * LPITCH + (c32 & 3) * 32 + 16 + gg * 8); \
        if (c32 == 4) { va00[s] = ONES4; va01[s] = ONES4; va10[s] = ONES4; va11[s] = ONES4; } \
    } while (0)

        LOADPAIR(0, 0);
#pragma unroll
        for (int pr = 0; pr < 8; ++pr) {
            const int s = pr & 1;         // compile-time under full unroll
            if (pr < 7) LOADPAIR(s ^ 1, pr + 1);

            const int t0 = pr * 2, t1 = t0 + 1;

            f32x16 sc0 = __builtin_amdgcn_mfma_f32_32x32x16_f16(
                __builtin_bit_cast(h8_t, ka0[s]), __builtin_bit_cast(h8_t, qa0[s]), z, 0, 0, 0);
            f32x16 sc1 = __builtin_amdgcn_mfma_f32_32x32x16_f16(
                __builtin_bit_cast(h8_t, ka1[s]), __builtin_bit_cast(h8_t, qa1[s]), z, 0, 0, 0);

            uint4 p00u, p01u, p10u, p11u;
            {
                float e[16];
#pragma unroll
                for (int r = 0; r < 16; ++r) e[r] = EXP2F(sc0[r]);
                p00u = make_uint4(pk16(e[0], e[1]),  pk16(e[2], e[3]),
                                  pk16(e[4], e[5]),  pk16(e[6], e[7]));
                p01u = make_uint4(pk16(e[8], e[9]),  pk16(e[10], e[11]),
                                  pk16(e[12], e[13]), pk16(e[14], e[15]));
            }
            {
                float e[16];
#pragma unroll
                for (int r = 0; r < 16; ++r) e[r] = EXP2F(sc1[r]);
                p10u = make_uint4(pk16(e[0], e[1]),  pk16(e[2], e[3]),
                                  pk16(e[4], e[5]),  pk16(e[6], e[7]));
                p11u = make_uint4(pk16(e[8], e[9]),  pk16(e[10], e[11]),
                                  pk16(e[12], e[13]), pk16(e[14], e[15]));
            }

            f32x16 pv0 = __builtin_amdgcn_mfma_f32_32x32x16_f16(
                __builtin_bit_cast(h8_t, va00[s]), __builtin_bit_cast(h8_t, p00u), z, 0, 0, 0);
            pv0 = __builtin_amdgcn_mfma_f32_32x32x16_f16(
                __builtin_bit_cast(h8_t, va01[s]), __builtin_bit_cast(h8_t, p01u), pv0, 0, 0, 0);
            f32x16 pv1 = __builtin_amdgcn_mfma_f32_32x32x16_f16(
                __builtin_bit_cast(h8_t, va10[s]), __builtin_bit_cast(h8_t, p10u), z, 0, 0, 0);
            pv1 = __builtin_amdgcn_mfma_f32_32x32x16_f16(
                __builtin_bit_cast(h8_t, va11[s]), __builtin_bit_cast(h8_t, p11u), pv1, 0, 0, 0);

            // denom at row 4 -> lane (c32,1) reg0; O[d] at lane (c32,0) regs0-3
            float s0 = __shfl(pv0[0], c32 + 32, 64);
            float s1 = __shfl(pv1[0], c32 + 32, 64);
            float r0 = RCPF(s0), r1 = RCPF(s1);
            if (lane < 32) {
                uint2 st0 = make_uint2(pk16(pv0[0] * r0, pv0[1] * r0),
                                       pk16(pv0[2] * r0, pv0[3] * r0));
                uint2 st1 = make_uint2(pk16(pv1[0] * r1, pv1[1] * r1),
                                       pk16(pv1[2] * r1, pv1[3] * r1));
                *(uint2*)(qsw + t0 * LPITCH + c32 * 4) = st0;  // attended aliases Q
                *(uint2*)(qsw + t1 * LPITCH + c32 * 4) = st1;
            }
        }
#undef LOADPAIR
    }
    // no barrier

    // ---------------- Phase 3: output projection + bias (A=Wo, B=at) -------
    // Depth-3 circular Wo prefetch.
    {
        h8_t af[4];
#pragma unroll
        for (int ks2 = 0; ks2 < 4; ++ks2)
            af[ks2] = *(const h8_t*)(qsw + c * LPITCH + ks2 * 32 + g * 8);

        h8_t wob[3][4];
#pragma unroll
        for (int p = 0; p < 3; ++p) {
            const __fp16* wb = wpk + ((size_t)((3 * 8 + p) * 4) * 64 + lane) * 8;
#pragma unroll
            for (int k = 0; k < 4; ++k)
                wob[p][k] = *(const h8_t*)(wb + (size_t)k * 64 * 8);
        }

#pragma unroll
        for (int nt = 0; nt < 8; ++nt) {
            const int slot = nt % 3;      // compile-time under full unroll
            f32x4 acc = {0.f, 0.f, 0.f, 0.f};
#pragma unroll
            for (int ks2 = 0; ks2 < 4; ++ks2)
                acc = __builtin_amdgcn_mfma_f32_16x16x32_f16(wob[slot][ks2], af[ks2], acc, 0, 0, 0);
            if (nt + 3 < 8) {
                const __fp16* wb = wpk + ((size_t)((3 * 8 + nt + 3) * 4) * 64 + lane) * 8;
#pragma unroll
                for (int k = 0; k < 4; ++k)
                    wob[slot][k] = *(const h8_t*)(wb + (size_t)k * 64 * 8);
            }
            int col0 = nt * 16 + g * 4;           // C[m=w_row][n=token c]
            float4 b4 = *(const float4*)(bo + col0);
            float4 st = make_float4(acc[0] + b4.x, acc[1] + b4.y,
                                    acc[2] + b4.z, acc[3] + b4.w);
            *(float4*)(out + (size_t)(tbase + c) * E + col0) = st;
        }
    }
}

// ---------------------------------------------------------------------------
extern "C" void kernel_launch(void* const* d_in, const int* in_sizes, int n_in,
                              void* d_out, int out_size, void* d_ws, size_t ws_size,
                              hipStream_t stream) {
    const float* x  = (const float*)d_in[0];
    const float* Wq = (const float*)d_in[1];
    const float* Wk = (const float*)d_in[2];
    const float* Wv = (const float*)d_in[3];
    const float* Wo = (const float*)d_in[4];
    const float* bo = (const float*)d_in[5];
    __fp16* wpk = (__fp16*)d_ws;   // 4*8*4*64*8 f16 = 128 KiB
    float* out = (float*)d_out;

    pack_w<<<32, 256, 0, stream>>>(Wq, Wk, Wv, Wo, wpk);
    mha_fused<<<TOKENS / (2 * WTOK), THREADS, 0, stream>>>(x, wpk, bo, out);
}

// Round 10
// 41.201 us; speedup vs baseline: 1.2120x; 1.0079x over previous
//
#include <hip/hip_runtime.h>

// MultiHeadAttention — fused per-token head-mixing attention.
// B=32, S=2048 -> 65536 tokens; E=128; HEADS=32; HEAD_DIM=4.
// out[t] = softmax_over_kh( Q(t)K(t)^T * 0.5 ) V(t)  @ Wo^T + bo.
//
// R10 (from 41.5us R9): SINGLE-VARIABLE experiment — unlock the register
// ceiling. R9's depth-3 prefetch + double-buffer never reached the ISA:
// VGPR_Count stayed 88 (identical to R8) because with no occupancy hint the
// compiler serializes to minimize registers. __launch_bounds__(128, 1)
// (min-waves=1: compiler MAY use many regs — the opposite of R2's forced-
// occupancy spill disaster) lets the prefetch/ILP actually materialize.
// Phase-1 prefetch deepened 3->4. Everything else bit-identical to R9.
// Validity check: VGPR must rise well above 88 and FETCH stay ~17MB.

#define TOKENS (32 * 2048)
#define E 128
#define NH 32
#define WTOK 16         // tokens per wave
#define THREADS 128     // 2 waves per block
#define LPITCH 136      // f16 elems per LDS token row (272 B)

typedef __attribute__((ext_vector_type(4))) float f32x4;
typedef __attribute__((ext_vector_type(16))) float f32x16;
typedef __fp16 h8_t __attribute__((ext_vector_type(8)));

#if __has_builtin(__builtin_amdgcn_exp2f)
#define EXP2F __builtin_amdgcn_exp2f
#else
#define EXP2F exp2f
#endif

#if __has_builtin(__builtin_amdgcn_rcpf)
#define RCPF __builtin_amdgcn_rcpf
#else
#define RCPF(x) (1.0f / (x))
#endif

static __device__ __forceinline__ unsigned pk16(float a, float b) {
    return __builtin_bit_cast(unsigned, __builtin_amdgcn_cvt_pkrtz(a, b));
}

static __device__ __forceinline__ f32x16 zero16() {
    f32x16 z;
#pragma unroll
    for (int i = 0; i < 16; ++i) z[i] = 0.f;
    return z;
}

// V' LDS permutation: p(kh) groups the 8 kh needed by PV A-fragment lane
// (c32,gg) half h into one contiguous 16B run at halfword offset d*32+16h+8gg.
static __device__ __forceinline__ int vperm(int kh) {
    return ((kh >> 4) & 1) * 16 + ((kh >> 2) & 1) * 8 + ((kh >> 3) & 1) * 4 + (kh & 3);
}

// ---------------------------------------------------------------------------
// Prelude: pack Wq,Wk,Wv,Wo (fp32, [out=128][in=128]) into f16 MFMA fragment
// order: wpk[proj][nt(8)][ks(4)][lane(64)][j(8)]; for lane l (c=l&15, g=l>>4):
// elem j = W[nt*16+c][ks*32 + g*8 + j].  Wk pre-scaled by 0.5*log2(e).
// ---------------------------------------------------------------------------
__global__ void pack_w(const float* __restrict__ Wq, const float* __restrict__ Wk,
                       const float* __restrict__ Wv, const float* __restrict__ Wo,
                       __fp16* __restrict__ wpk) {
    int idx = blockIdx.x * blockDim.x + threadIdx.x;   // 4*8*4*64 = 8192
    if (idx >= 4 * 8 * 4 * 64) return;
    int lane = idx & 63;
    int ks   = (idx >> 6) & 3;
    int nt   = (idx >> 8) & 7;
    int proj = idx >> 11;
    const float* W = (proj == 0) ? Wq : (proj == 1) ? Wk : (proj == 2) ? Wv : Wo;
    float scl = (proj == 1) ? 0.72134752044448170f : 1.0f;  // 0.5*log2(e)
    int c = lane & 15, g = lane >> 4;
    const float* src = W + (size_t)(nt * 16 + c) * E + ks * 32 + g * 8;
    __fp16* dst = wpk + (size_t)idx * 8;
#pragma unroll
    for (int j = 0; j < 8; ++j) dst[j] = (__fp16)(src[j] * scl);
}

// ---------------------------------------------------------------------------
// Main fused kernel: 2 independent 16-token waves per block, no barriers.
// __launch_bounds__(128, 1): allow high VGPR so prefetch/ILP can materialize.
// ---------------------------------------------------------------------------
__global__ __launch_bounds__(THREADS, 1) void mha_fused(
        const float* __restrict__ x, const __fp16* __restrict__ wpk,
        const float* __restrict__ bo, float* __restrict__ out) {
    __shared__ __align__(16) __fp16 qs [2 * WTOK * LPITCH];  // Q rows -> attended
    __shared__ __align__(16) __fp16 ksh[2 * WTOK * LPITCH];  // K*cexp [tok][kh*4+d]
    __shared__ __align__(16) __fp16 vth[2 * WTOK * LPITCH];  // V'' [tok][d*32+p(kh)]

    const int tid  = threadIdx.x;
    const int wave = tid >> 6;
    const int lane = tid & 63;
    const int c = lane & 15, g = lane >> 4;
    const int tbase = blockIdx.x * (2 * WTOK) + wave * WTOK;  // wave's first token

    __fp16* qsw = qs  + wave * WTOK * LPITCH;   // wave-private LDS slices
    __fp16* ksw = ksh + wave * WTOK * LPITCH;
    __fp16* vtw = vth + wave * WTOK * LPITCH;

    // ---------------- Phase 1: all 24 QKV column-tiles for own 16 tokens ---
    // Depth-4 circular prefetch of weight fragments (address nc = proj*8+nt).
    {
        h8_t afrag[4];     // x fragments, lane c = token, kappa(g,j)=g*8+j
        const float* xrow = x + (size_t)(tbase + c) * E;
#pragma unroll
        for (int ks2 = 0; ks2 < 4; ++ks2) {
            const float* p = xrow + ks2 * 32 + g * 8;
            float4 v0 = *(const float4*)(p);
            float4 v1 = *(const float4*)(p + 4);
            uint4 au;
            au.x = pk16(v0.x, v0.y);
            au.y = pk16(v0.z, v0.w);
            au.z = pk16(v1.x, v1.y);
            au.w = pk16(v1.z, v1.w);
            afrag[ks2] = __builtin_bit_cast(h8_t, au);
        }

        h8_t wfb[4][4];    // circular prefetch buffers (depth 4)
#pragma unroll
        for (int p = 0; p < 4; ++p) {
            const __fp16* wb = wpk + ((size_t)(p * 4) * 64 + lane) * 8;
#pragma unroll
            for (int k = 0; k < 4; ++k)
                wfb[p][k] = *(const h8_t*)(wb + (size_t)k * 64 * 8);
        }

#pragma unroll
        for (int nc = 0; nc < 24; ++nc) {
            const int proj = nc >> 3;     // 0:Q 1:K 2:V (compile-time)
            const int nt   = nc & 7;
            const int slot = nc & 3;      // compile-time under full unroll
            f32x4 acc = {0.f, 0.f, 0.f, 0.f};
#pragma unroll
            for (int ks2 = 0; ks2 < 4; ++ks2) {
                // A=W (m=w_row), B=x (n=token): C[m=g*4+r2 (+nt*16)][n=c]
                acc = __builtin_amdgcn_mfma_f32_16x16x32_f16(wfb[slot][ks2], afrag[ks2], acc, 0, 0, 0);
            }
            if (nc + 4 < 24) {            // refill this slot for nc+4
                const __fp16* wb = wpk + ((size_t)((nc + 4) * 4) * 64 + lane) * 8;
#pragma unroll
                for (int k = 0; k < 4; ++k)
                    wfb[slot][k] = *(const h8_t*)(wb + (size_t)k * 64 * 8);
            }
            if (proj < 2) {
                __fp16* dst = proj ? ksw : qsw;
                uint2 st = make_uint2(pk16(acc[0], acc[1]), pk16(acc[2], acc[3]));
                *(uint2*)(dst + c * LPITCH + nt * 16 + g * 4) = st;   // one b64
            } else {
                int vp = vperm(nt * 4 + g);   // kh = nt*4+g, d = r2
#pragma unroll
                for (int r2 = 0; r2 < 4; ++r2)
                    vtw[c * LPITCH + r2 * 32 + vp] = (__fp16)acc[r2];
            }
        }
    }
    // no barrier: same-wave LDS RAW ordered by lgkmcnt

    // ---------------- Phase 2: per-token attention, 2-token ILP ------------
    // S^T[kh][qh] = mfma32x32(A=K', B=Q) (k=d in slots 0-3);
    // O/denom     = mfma32x32(A=V'+ones-row4, B=exp(S)) x2 halves.
    // Double-buffered inputs: pair pr+1's LDS loads issue before pair pr's
    // compute; exp/pack block hides the LDS latency.
    {
        const int c32 = lane & 31;
        const int gg  = lane >> 5;
        const uint4 ONES4 = make_uint4(0x3C003C00u, 0x3C003C00u, 0x3C003C00u, 0x3C003C00u);
        const f32x16 z = zero16();

        uint4 ka0[2], qa0[2], ka1[2], qa1[2];
        uint4 va00[2], va01[2], va10[2], va11[2];

#define LOADPAIR(s, pr_) do {                                                  \
        const int t0_ = (pr_) * 2, t1_ = t0_ + 1;                              \
        ka0[s] = qa0[s] = ka1[s] = qa1[s] = make_uint4(0u, 0u, 0u, 0u);        \
        if (gg == 0) {                                                         \
            uint2 t_;                                                          \
            t_ = *(const uint2*)(ksw + t0_ * LPITCH + c32 * 4); ka0[s].x = t_.x; ka0[s].y = t_.y; \
            t_ = *(const uint2*)(qsw + t0_ * LPITCH + c32 * 4); qa0[s].x = t_.x; qa0[s].y = t_.y; \
            t_ = *(const uint2*)(ksw + t1_ * LPITCH + c32 * 4); ka1[s].x = t_.x; ka1[s].y = t_.y; \
            t_ = *(const uint2*)(qsw + t1_ * LPITCH + c32 * 4); qa1[s].x = t_.x; qa1[s].y = t_.y; \
        }                                                                      \
        va00[s] = *(const uint4*)(vtw + t0_ * LPITCH + (c32 & 3) * 32 + gg * 8);      \
        va01[s] = *(const uint4*)(vtw + t0_ * LPITCH + (c32 & 3) * 32 + 16 + gg * 8); \
        va10[s] = *(const uint4*)(vtw + t1_ * LPITCH + (c32 & 3) * 32 + gg * 8);      \
        va11[s] = *(const uint4*)(vtw + t1_ * LPITCH + (c32 & 3) * 32 + 16 + gg * 8); \
        if (c32 == 4) { va00[s] = ONES4; va01[s] = ONES4; va10[s] = ONES4; va11[s] = ONES4; } \
    } while (0)

        LOADPAIR(0, 0);
#pragma unroll
        for (int pr = 0; pr < 8; ++pr) {
            const int s = pr & 1;         // compile-time under full unroll
            if (pr < 7) LOADPAIR(s ^ 1, pr + 1);

            const int t0 = pr * 2, t1 = t0 + 1;

            f32x16 sc0 = __builtin_amdgcn_mfma_f32_32x32x16_f16(
                __builtin_bit_cast(h8_t, ka0[s]), __builtin_bit_cast(h8_t, qa0[s]), z, 0, 0, 0);
            f32x16 sc1 = __builtin_amdgcn_mfma_f32_32x32x16_f16(
                __builtin_bit_cast(h8_t, ka1[s]), __builtin_bit_cast(h8_t, qa1[s]), z, 0, 0, 0);

            uint4 p00u, p01u, p10u, p11u;
            {
                float e[16];
#pragma unroll
                for (int r = 0; r < 16; ++r) e[r] = EXP2F(sc0[r]);
                p00u = make_uint4(pk16(e[0], e[1]),  pk16(e[2], e[3]),
                                  pk16(e[4], e[5]),  pk16(e[6], e[7]));
                p01u = make_uint4(pk16(e[8], e[9]),  pk16(e[10], e[11]),
                                  pk16(e[12], e[13]), pk16(e[14], e[15]));
            }
            {
                float e[16];
#pragma unroll
                for (int r = 0; r < 16; ++r) e[r] = EXP2F(sc1[r]);
                p10u = make_uint4(pk16(e[0], e[1]),  pk16(e[2], e[3]),
                                  pk16(e[4], e[5]),  pk16(e[6], e[7]));
                p11u = make_uint4(pk16(e[8], e[9]),  pk16(e[10], e[11]),
                                  pk16(e[12], e[13]), pk16(e[14], e[15]));
            }

            f32x16 pv0 = __builtin_amdgcn_mfma_f32_32x32x16_f16(
                __builtin_bit_cast(h8_t, va00[s]), __builtin_bit_cast(h8_t, p00u), z, 0, 0, 0);
            pv0 = __builtin_amdgcn_mfma_f32_32x32x16_f16(
                __builtin_bit_cast(h8_t, va01[s]), __builtin_bit_cast(h8_t, p01u), pv0, 0, 0, 0);
            f32x16 pv1 = __builtin_amdgcn_mfma_f32_32x32x16_f16(
                __builtin_bit_cast(h8_t, va10[s]), __builtin_bit_cast(h8_t, p10u), z, 0, 0, 0);
            pv1 = __builtin_amdgcn_mfma_f32_32x32x16_f16(
                __builtin_bit_cast(h8_t, va11[s]), __builtin_bit_cast(h8_t, p11u), pv1, 0, 0, 0);

            // denom at row 4 -> lane (c32,1) reg0; O[d] at lane (c32,0) regs0-3
            float s0 = __shfl(pv0[0], c32 + 32, 64);
            float s1 = __shfl(pv1[0], c32 + 32, 64);
            float r0 = RCPF(s0), r1 = RCPF(s1);
            if (lane < 32) {
                uint2 st0 = make_uint2(pk16(pv0[0] * r0, pv0[1] * r0),
                                       pk16(pv0[2] * r0, pv0[3] * r0));
                uint2 st1 = make_uint2(pk16(pv1[0] * r1, pv1[1] * r1),
                                       pk16(pv1[2] * r1, pv1[3] * r1));
                *(uint2*)(qsw + t0 * LPITCH + c32 * 4) = st0;  // attended aliases Q
                *(uint2*)(qsw + t1 * LPITCH + c32 * 4) = st1;
            }
        }
#undef LOADPAIR
    }
    // no barrier

    // ---------------- Phase 3: output projection + bias (A=Wo, B=at) -------
    // Depth-3 circular Wo prefetch.
    {
        h8_t af[4];
#pragma unroll
        for (int ks2 = 0; ks2 < 4; ++ks2)
            af[ks2] = *(const h8_t*)(qsw + c * LPITCH + ks2 * 32 + g * 8);

        h8_t wob[3][4];
#pragma unroll
        for (int p = 0; p < 3; ++p) {
            const __fp16* wb = wpk + ((size_t)((3 * 8 + p) * 4) * 64 + lane) * 8;
#pragma unroll
            for (int k = 0; k < 4; ++k)
                wob[p][k] = *(const h8_t*)(wb + (size_t)k * 64 * 8);
        }

#pragma unroll
        for (int nt = 0; nt < 8; ++nt) {
            const int slot = nt % 3;      // compile-time under full unroll
            f32x4 acc = {0.f, 0.f, 0.f, 0.f};
#pragma unroll
            for (int ks2 = 0; ks2 < 4; ++ks2)
                acc = __builtin_amdgcn_mfma_f32_16x16x32_f16(wob[slot][ks2], af[ks2], acc, 0, 0, 0);
            if (nt + 3 < 8) {
                const __fp16* wb = wpk + ((size_t)((3 * 8 + nt + 3) * 4) * 64 + lane) * 8;
#pragma unroll
                for (int k = 0; k < 4; ++k)
                    wob[slot][k] = *(const h8_t*)(wb + (size_t)k * 64 * 8);
            }
            int col0 = nt * 16 + g * 4;           // C[m=w_row][n=token c]
            float4 b4 = *(const float4*)(bo + col0);
            float4 st = make_float4(acc[0] + b4.x, acc[1] + b4.y,
                                    acc[2] + b4.z, acc[3] + b4.w);
            *(float4*)(out + (size_t)(tbase + c) * E + col0) = st;
        }
    }
}

// ---------------------------------------------------------------------------
extern "C" void kernel_launch(void* const* d_in, const int* in_sizes, int n_in,
                              void* d_out, int out_size, void* d_ws, size_t ws_size,
                              hipStream_t stream) {
    const float* x  = (const float*)d_in[0];
    const float* Wq = (const float*)d_in[1];
    const float* Wk = (const float*)d_in[2];
    const float* Wv = (const float*)d_in[3];
    const float* Wo = (const float*)d_in[4];
    const float* bo = (const float*)d_in[5];
    __fp16* wpk = (__fp16*)d_ws;   // 4*8*4*64*8 f16 = 128 KiB
    float* out = (float*)d_out;

    pack_w<<<32, 256, 0, stream>>>(Wq, Wk, Wv, Wo, wpk);
    mha_fused<<<TOKENS / (2 * WTOK), THREADS, 0, stream>>>(x, wpk, bo, out);
}